// Round 8
// baseline (229.990 us; speedup 1.0000x reference)
//
#include <hip/hip_runtime.h>

// Fused: X->QKV proj (fp16 MFMA) -> RoPE -> GQA causal flash attn -> out proj.
// B=2 T=2048 D=2048 NQ=16 NK=4 H=128, scale=1.0 (no 1/sqrt(H)).

typedef _Float16 half8 __attribute__((ext_vector_type(8)));
typedef _Float16 half4 __attribute__((ext_vector_type(4)));
typedef float f32x4 __attribute__((ext_vector_type(4)));

#define GLOAD16(gp, lp) \
  __builtin_amdgcn_global_load_lds((__attribute__((address_space(1))) void*)(gp), \
                                   (__attribute__((address_space(3))) void*)(lp), 16, 0, 0)

#define WAIT_VM8() asm volatile("s_waitcnt vmcnt(8)" ::: "memory")
#define WAIT_VM0() asm volatile("s_waitcnt vmcnt(0)" ::: "memory")
#define BAR() asm volatile("s_barrier" ::: "memory")

static constexpr int T_   = 2048;
static constexpr int D_   = 2048;
static constexpr int NQ_  = 16;
static constexpr int NK_  = 4;
static constexpr int H_   = 128;
static constexpr int NQKV = 3072;   // 16*128 + 4*128 + 4*128
static constexpr int KOFF = 2048;
static constexpr int VOFF = 2560;

// ---------------- prep kernels ----------------

__global__ void cast_x_kernel(const float* __restrict__ in, _Float16* __restrict__ out) {
  int i = (blockIdx.x * 256 + threadIdx.x) * 4;
  float4 v = *reinterpret_cast<const float4*>(in + i);
  union { _Float16 h[4]; uint2 u; } p;
  p.h[0] = (_Float16)v.x; p.h[1] = (_Float16)v.y;
  p.h[2] = (_Float16)v.z; p.h[3] = (_Float16)v.w;
  *reinterpret_cast<uint2*>(out + i) = p.u;
}

// in: [2048][ncols] f32  ->  out: [ncols][2048] f16 (row stride 2048)
__global__ void transpose_cast_kernel(const float* __restrict__ in,
                                      _Float16* __restrict__ out, int ncols) {
  __shared__ float tile[32][33];
  int n0 = blockIdx.x * 32, k0 = blockIdx.y * 32;
  int tx = threadIdx.x, ty = threadIdx.y;
#pragma unroll
  for (int i = 0; i < 32; i += 8)
    tile[ty + i][tx] = in[(size_t)(k0 + ty + i) * ncols + (n0 + tx)];
  __syncthreads();
#pragma unroll
  for (int i = 0; i < 32; i += 8)
    out[(size_t)(n0 + ty + i) * 2048 + (k0 + tx)] = (_Float16)tile[tx][ty + i];
}

// RoPE in-place on Q (heads 0..15) and K (heads 16..19) sections of QKV buf.
__global__ void rope_kernel(_Float16* __restrict__ qkv, const int* __restrict__ pos) {
  int idx = blockIdx.x * 256 + threadIdx.x;   // < 4096*20*64
  int h = idx & 63;
  int head = (idx >> 6) % 20;
  int m = idx / (64 * 20);
  float p = (float)pos[m];
  float freq = expf(-0.14391156831f * (float)h);   // 10000^(-h/64)
  float a = p * freq;
  float s, c;
  sincosf(a, &s, &c);
  int col = (head < 16) ? (head * H_ + h) : (KOFF + (head - 16) * H_ + h);
  _Float16* ptr = qkv + (size_t)m * NQKV + col;
  float x1 = (float)ptr[0], x2 = (float)ptr[64];
  ptr[0]  = (_Float16)(x1 * c - x2 * s);
  ptr[64] = (_Float16)(x2 * c + x1 * s);
}

// V section of QKV [m][2560+kh*128+h] -> Vt [b][kh][h][t]
__global__ void vtrans_kernel(const _Float16* __restrict__ qkv, _Float16* __restrict__ vt) {
  __shared__ _Float16 tile[32][33];
  int t0 = blockIdx.x * 32, h0 = blockIdx.y * 32;
  int slab = blockIdx.z;  // b*4 + kh
  int tx = threadIdx.x, ty = threadIdx.y;
  int b = slab >> 2, kh = slab & 3;
#pragma unroll
  for (int i = 0; i < 32; i += 8)
    tile[ty + i][tx] = qkv[(size_t)(b * T_ + t0 + ty + i) * NQKV + VOFF + kh * H_ + h0 + tx];
  __syncthreads();
#pragma unroll
  for (int i = 0; i < 32; i += 8)
    vt[(size_t)(slab * H_ + h0 + ty + i) * T_ + (t0 + tx)] = tile[tx][ty + i];
}

// ---------------- 8-phase GEMM: C[M,N] = A[M,K] * Bt[N,K]^T ----------------
// BM=256, BK=64, 8 waves (2M x 4N); BN=256 (4 phases/K-tile) or 128 (2 phases).
// Per phase: {ds_read frags; BAR; setprio1; 16 MFMA; setprio0; BAR} (T3+T5).
// Counted vmcnt once per K-tile (T4): one stage (NL loads) stays in flight,
// issued right after its buffer frees. XOR-swizzle unit^=(row&7) via
// pre-swizzled global source (T2 / rule 21). Bijective XCD swizzle (T1).

template <int BN, int OUT_F32>
__global__ __launch_bounds__(512, 1) void gemm256_kernel(const _Float16* __restrict__ A,
                                                         const _Float16* __restrict__ Bt,
                                                         void* __restrict__ Cout,
                                                         int N, int K, int nbx) {
  constexpr int NTN = BN / 64;            // n-tiles per wave: 4 or 2
  constexpr int MH  = (BN == 256) ? 2 : 1;
  constexpr int MPP = 8 / MH;             // m-tiles per phase: 4 or 8
  constexpr int NLB = BN / 64;            // B gloads per thread per tile
  __shared__ __align__(16) _Float16 As[2][256 * 64];
  __shared__ __align__(16) _Float16 Bs[2][BN * 64];
  const int tid = threadIdx.x;
  const int wave = tid >> 6, lane = tid & 63;
  const int lg = lane >> 4, lm = lane & 15;
  const int cpx = gridDim.x >> 3;
  const int swz = ((int)blockIdx.x & 7) * cpx + ((int)blockIdx.x >> 3);
  const int brow = (swz / nbx) * 256, bcol = (swz % nbx) * BN;
  const int wr = wave >> 2, wc = wave & 3;
  constexpr int WN = BN / 4;              // per-wave N extent
  f32x4 acc[8][NTN] = {};
  const int NT2 = K >> 6;

  auto stage = [&](int kt, int buf) {
    const int k0 = kt * 64;
#pragma unroll
    for (int j = 0; j < 4; ++j) {         // A: 256 rows x 8 units
      int U = j * 512 + tid;
      int row = U >> 3, u = U & 7;
      int us = u ^ (row & 7);
      GLOAD16(A + (size_t)(brow + row) * K + k0 + us * 8,
              (char*)&As[buf][0] + ((j * 512 + wave * 64) << 4));
    }
#pragma unroll
    for (int j = 0; j < NLB; ++j) {       // B: BN rows x 8 units
      int U = j * 512 + tid;
      int row = U >> 3, u = U & 7;
      int us = u ^ (row & 7);
      GLOAD16(Bt + (size_t)(bcol + row) * K + k0 + us * 8,
              (char*)&Bs[buf][0] + ((j * 512 + wave * 64) << 4));
    }
  };

  stage(0, 0);
  stage(1, 1);
  for (int kt = 0; kt < NT2; ++kt) {
    const int cur = kt & 1;
    if (kt + 1 < NT2) {
      if constexpr (BN == 256) asm volatile("s_waitcnt vmcnt(8)" ::: "memory");
      else                     asm volatile("s_waitcnt vmcnt(6)" ::: "memory");
    } else {
      WAIT_VM0();
    }
    BAR();
    const _Float16* Asb = &As[cur][0];
    const _Float16* Bsb = &Bs[cur][0];
#pragma unroll
    for (int kk = 0; kk < 2; ++kk) {
      half8 bf[NTN];
#pragma unroll
      for (int nt = 0; nt < NTN; ++nt) {
        int row = wc * WN + nt * 16 + lm;
        int u = (kk * 4 + lg) ^ (row & 7);
        bf[nt] = *reinterpret_cast<const half8*>(Bsb + row * 64 + u * 8);
      }
#pragma unroll
      for (int mh = 0; mh < MH; ++mh) {
        half8 af[MPP];
#pragma unroll
        for (int mt = 0; mt < MPP; ++mt) {
          int row = wr * 128 + (mh * MPP + mt) * 16 + lm;
          int u = (kk * 4 + lg) ^ (row & 7);
          af[mt] = *reinterpret_cast<const half8*>(Asb + row * 64 + u * 8);
        }
        BAR();
        __builtin_amdgcn_s_setprio(1);
#pragma unroll
        for (int mt = 0; mt < MPP; ++mt)
#pragma unroll
          for (int nt = 0; nt < NTN; ++nt)
            acc[mh * MPP + mt][nt] = __builtin_amdgcn_mfma_f32_16x16x32_f16(
                af[mt], bf[nt], acc[mh * MPP + mt][nt], 0, 0, 0);
        __builtin_amdgcn_s_setprio(0);
        BAR();
      }
    }
    if (kt + 2 < NT2) stage(kt + 2, cur);
  }

#pragma unroll
  for (int mt = 0; mt < 8; ++mt)
#pragma unroll
    for (int nt = 0; nt < NTN; ++nt)
#pragma unroll
      for (int r = 0; r < 4; ++r) {
        size_t row = brow + wr * 128 + mt * 16 + lg * 4 + r;
        size_t col = bcol + wc * WN + nt * 16 + lm;
        if constexpr (OUT_F32) ((float*)Cout)[row * N + col] = acc[mt][nt][r];
        else ((_Float16*)Cout)[row * N + col] = (_Float16)acc[mt][nt][r];
      }
}

// ---------------- flash attention (round-3 best: 72 us) ----------------
// Uniform-work blocks: q-tile = 64 rows (wave owns 16), tiles paired (p, 31-p).
// Swapped QK^T (mfma(K,Q)): lane owns one q-row (q=qbase+lm), 16 s-values ->
// row-reduce = 15 local ops + 2 shfl. exp2 w/ log2e folded into Q. Defer-max
// (THR=14 log2 units, P<=2^14 fits f16) skips O-rescale on most iters.

__global__ __launch_bounds__(256, 2) void attn_kernel(const _Float16* __restrict__ qkv,
                                                      const _Float16* __restrict__ vt,
                                                      _Float16* __restrict__ attn) {
  __shared__ __align__(16) _Float16 Ks[2][64 * 128];    // [s][h], 16 units/row, u^= s&15
  __shared__ __align__(16) _Float16 Vs[2][128 * 64];    // [h][s],  8 units/row, u^= h&7
  __shared__ __align__(16) _Float16 Ps[4][16 * 64];     // per-wave [q][s], u^= q&7
  const int bid = blockIdx.x;
  const int swz = (bid & 7) * 64 + (bid >> 3);          // XCD chunk = 64 consecutive swz
  const int chunk = swz >> 6;                           // = b*4 + kh
  const int b = chunk >> 2, kh = chunk & 3;
  const int n = kh * 4 + ((swz >> 4) & 3);
  const int p = swz & 15;                               // pair index
  const int tid = threadIdx.x, wave = tid >> 6, lane = tid & 63;
  const int lg = lane >> 4, lm = lane & 15;

  auto stage = [&](int j, int buf) {
    const int s0 = j * 64;
    char* Kb = (char*)&Ks[buf][0];
    char* Vb = (char*)&Vs[buf][0];
#pragma unroll
    for (int jj = 0; jj < 4; ++jj) {   // K tile: 64 rows x 16 units
      int U = jj * 256 + tid;
      int srow = U >> 4, u = U & 15;
      int us = u ^ (srow & 15);
      GLOAD16(qkv + (size_t)(b * T_ + s0 + srow) * NQKV + KOFF + kh * H_ + us * 8,
              Kb + ((jj * 256 + wave * 64) << 4));
    }
#pragma unroll
    for (int jj = 0; jj < 4; ++jj) {   // Vt tile: 128 rows x 8 units
      int U = jj * 256 + tid;
      int hrow = U >> 3, u = U & 7;
      int us = u ^ (hrow & 7);
      GLOAD16(vt + (size_t)((b * NK_ + kh) * H_ + hrow) * T_ + s0 + us * 8,
              Vb + ((jj * 256 + wave * 64) << 4));
    }
  };

  for (int ph = 0; ph < 2; ++ph) {
    const int t = ph ? (31 - p) : p;                    // q-tile index, rows [64t, 64t+63]
    const int qbase = t * 64 + wave * 16;

    // Q fragments, scaled by log2(e) in f32 so QK^T logits are in log2 units.
    half8 qf[4];
    const _Float16* qptr = qkv + (size_t)(b * T_ + qbase + lm) * NQKV + n * H_;
#pragma unroll
    for (int kk = 0; kk < 4; ++kk) {
      half8 qr = *reinterpret_cast<const half8*>(qptr + kk * 32 + lg * 8);
#pragma unroll
      for (int j = 0; j < 8; ++j)
        qf[kk][j] = (_Float16)((float)qr[j] * 1.4426950408889634f);
    }

    f32x4 o[8] = {};
    float mrow_s = -1e30f, lrow_s = 0.f;

    const int nkv = t + 1;
    stage(0, 0);
    for (int it = 0; it < nkv; ++it) {
      const int cur = it & 1;
      if (it + 1 < nkv) { stage(it + 1, cur ^ 1); WAIT_VM8(); }
      else              { WAIT_VM0(); }
      BAR();
      const _Float16* Kt = &Ks[cur][0];
      const _Float16* Vt2 = &Vs[cur][0];

      // Swapped QK^T: S[ns][r] = logit(q = qbase+lm, s = it*64 + ns*16 + lg*4 + r)
      f32x4 S[4];
      __builtin_amdgcn_s_setprio(1);
#pragma unroll
      for (int ns = 0; ns < 4; ++ns) {
        half8 kf[4];
        int srow = ns * 16 + lm;
#pragma unroll
        for (int kk = 0; kk < 4; ++kk) {
          int u = (kk * 4 + lg) ^ (srow & 15);
          kf[kk] = *reinterpret_cast<const half8*>(Kt + srow * 128 + u * 8);
        }
        f32x4 a = {0.f, 0.f, 0.f, 0.f};
#pragma unroll
        for (int kk = 0; kk < 4; ++kk)
          a = __builtin_amdgcn_mfma_f32_16x16x32_f16(kf[kk], qf[kk], a, 0, 0, 0);
        S[ns] = a;
      }
      __builtin_amdgcn_s_setprio(0);

      if (it == t) {                  // diagonal tile: causal mask
        const int q = qbase + lm;
#pragma unroll
        for (int ns = 0; ns < 4; ++ns)
#pragma unroll
          for (int r = 0; r < 4; ++r) {
            int s = t * 64 + ns * 16 + lg * 4 + r;
            if (s > q) S[ns][r] = -1e30f;
          }
      }

      // Row max: 15 local fmax + 2 shfl (lanes xor16/xor32 share the q-row).
      float pm0 = fmaxf(fmaxf(S[0][0], S[0][1]), fmaxf(S[0][2], S[0][3]));
      float pm1 = fmaxf(fmaxf(S[1][0], S[1][1]), fmaxf(S[1][2], S[1][3]));
      float pm2 = fmaxf(fmaxf(S[2][0], S[2][1]), fmaxf(S[2][2], S[2][3]));
      float pm3 = fmaxf(fmaxf(S[3][0], S[3][1]), fmaxf(S[3][2], S[3][3]));
      float pm = fmaxf(fmaxf(pm0, pm1), fmaxf(pm2, pm3));
      pm = fmaxf(pm, __shfl_xor(pm, 16));
      pm = fmaxf(pm, __shfl_xor(pm, 32));

      // Defer-max: only rescale when some row's max grew past THR (log2 units).
      if (__any(pm > mrow_s + 14.f)) {
        float mn = fmaxf(mrow_s, pm);
        float sc = __builtin_amdgcn_exp2f(mrow_s - mn);
        mrow_s = mn;
        lrow_s *= sc;
        float scr[4];
#pragma unroll
        for (int r = 0; r < 4; ++r) scr[r] = __shfl(sc, lg * 4 + r);
#pragma unroll
        for (int nh = 0; nh < 8; ++nh)
#pragma unroll
          for (int r = 0; r < 4; ++r) o[nh][r] *= scr[r];
      }

      const float m = mrow_s;
      float ps = 0.f;
#pragma unroll
      for (int ns = 0; ns < 4; ++ns)
#pragma unroll
        for (int r = 0; r < 4; ++r) {
          float pv = __builtin_amdgcn_exp2f(S[ns][r] - m);
          S[ns][r] = pv;
          ps += pv;
        }
      ps += __shfl_xor(ps, 16);
      ps += __shfl_xor(ps, 32);
      lrow_s += ps;

      // P -> LDS: 4x ds_write_b64 (packed half4), same XOR swizzle as PA read.
#pragma unroll
      for (int ns = 0; ns < 4; ++ns) {
        half4 pk;
#pragma unroll
        for (int r = 0; r < 4; ++r) pk[r] = (_Float16)S[ns][r];
        int u = (2 * ns + (lg >> 1)) ^ (lm & 7);
        *reinterpret_cast<half4*>(&Ps[wave][lm * 64 + u * 8 + (lg & 1) * 4]) = pk;
      }

      __builtin_amdgcn_s_setprio(1);
#pragma unroll
      for (int kk2 = 0; kk2 < 2; ++kk2) {
        int up = (kk2 * 4 + lg) ^ (lm & 7);
        half8 pa = *reinterpret_cast<const half8*>(&Ps[wave][lm * 64 + up * 8]);
#pragma unroll
        for (int nh = 0; nh < 8; ++nh) {
          int hrow = nh * 16 + lm;
          int u = (kk2 * 4 + lg) ^ (hrow & 7);
          half8 vf = *reinterpret_cast<const half8*>(Vt2 + hrow * 64 + u * 8);
          o[nh] = __builtin_amdgcn_mfma_f32_16x16x32_f16(pa, vf, o[nh], 0, 0, 0);
        }
      }
      __builtin_amdgcn_s_setprio(0);
      BAR();
    }

    float linv[4];
#pragma unroll
    for (int r = 0; r < 4; ++r) linv[r] = 1.f / __shfl(lrow_s, lg * 4 + r);
#pragma unroll
    for (int r = 0; r < 4; ++r) {
      int q = qbase + lg * 4 + r;
      _Float16* optr = attn + ((size_t)(b * T_ + q) * NQ_ + n) * H_ + lm;
#pragma unroll
      for (int nh = 0; nh < 8; ++nh)
        optr[nh * 16] = (_Float16)(o[nh][r] * linv[r]);
    }
  }
}

// ---------------- launch ----------------

extern "C" void kernel_launch(void* const* d_in, const int* in_sizes, int n_in,
                              void* d_out, int out_size, void* d_ws, size_t ws_size,
                              hipStream_t stream) {
  const float* X  = (const float*)d_in[0];
  const int* pos  = (const int*)d_in[1];
  const float* Wq = (const float*)d_in[2];
  const float* Wk = (const float*)d_in[3];
  const float* Wv = (const float*)d_in[4];
  const float* Wo = (const float*)d_in[5];

  _Float16* Xh    = (_Float16*)d_ws;                   // 4096*2048
  _Float16* Wqkvt = Xh + (size_t)4096 * 2048;          // [3072][2048]
  _Float16* Wot   = Wqkvt + (size_t)3072 * 2048;       // [2048][2048]
  _Float16* QKV   = Wot + (size_t)2048 * 2048;         // [4096][3072]
  _Float16* Vt    = QKV + (size_t)4096 * 3072;         // [2][4][128][2048]
  _Float16* Attn  = Vt + (size_t)8 * 128 * 2048;       // [4096][2048]

  dim3 tb(32, 8);
  cast_x_kernel<<<8192, 256, 0, stream>>>(X, Xh);
  transpose_cast_kernel<<<dim3(64, 64), tb, 0, stream>>>(Wq, Wqkvt, 2048);
  transpose_cast_kernel<<<dim3(16, 64), tb, 0, stream>>>(Wk, Wqkvt + (size_t)2048 * 2048, 512);
  transpose_cast_kernel<<<dim3(16, 64), tb, 0, stream>>>(Wv, Wqkvt + (size_t)2560 * 2048, 512);
  transpose_cast_kernel<<<dim3(64, 64), tb, 0, stream>>>(Wo, Wot, 2048);

  gemm256_kernel<256, 0><<<192, 512, 0, stream>>>(Xh, Wqkvt, QKV, NQKV, 2048, 12);
  rope_kernel<<<20480, 256, 0, stream>>>(QKV, pos);
  vtrans_kernel<<<dim3(64, 4, 8), tb, 0, stream>>>(QKV, Vt);
  attn_kernel<<<512, 256, 0, stream>>>(QKV, Vt, Attn);
  gemm256_kernel<128, 1><<<256, 512, 0, stream>>>(Attn, Wot, d_out, 2048, 2048, 16);
}

// Round 9
// 201.982 us; speedup vs baseline: 1.1387x; 1.1387x over previous
//
#include <hip/hip_runtime.h>

// Fused: X->QKV proj (fp16 MFMA) -> RoPE -> GQA causal flash attn -> out proj.
// B=2 T=2048 D=2048 NQ=16 NK=4 H=128, scale=1.0 (no 1/sqrt(H)).

typedef _Float16 half8 __attribute__((ext_vector_type(8)));
typedef _Float16 half4 __attribute__((ext_vector_type(4)));
typedef float f32x4 __attribute__((ext_vector_type(4)));

#define GLOAD16(gp, lp) \
  __builtin_amdgcn_global_load_lds((__attribute__((address_space(1))) void*)(gp), \
                                   (__attribute__((address_space(3))) void*)(lp), 16, 0, 0)

#define WAIT_VM8() asm volatile("s_waitcnt vmcnt(8)" ::: "memory")
#define WAIT_VM0() asm volatile("s_waitcnt vmcnt(0)" ::: "memory")
#define BAR() asm volatile("s_barrier" ::: "memory")

static constexpr int T_   = 2048;
static constexpr int D_   = 2048;
static constexpr int NQ_  = 16;
static constexpr int NK_  = 4;
static constexpr int H_   = 128;
static constexpr int NQKV = 3072;   // 16*128 + 4*128 + 4*128
static constexpr int KOFF = 2048;
static constexpr int VOFF = 2560;

// ---------------- prep kernels ----------------

__global__ void cast_x_kernel(const float* __restrict__ in, _Float16* __restrict__ out) {
  int i = (blockIdx.x * 256 + threadIdx.x) * 4;
  float4 v = *reinterpret_cast<const float4*>(in + i);
  union { _Float16 h[4]; uint2 u; } p;
  p.h[0] = (_Float16)v.x; p.h[1] = (_Float16)v.y;
  p.h[2] = (_Float16)v.z; p.h[3] = (_Float16)v.w;
  *reinterpret_cast<uint2*>(out + i) = p.u;
}

// in: [2048][ncols] f32  ->  out: [ncols][2048] f16 (row stride 2048)
__global__ void transpose_cast_kernel(const float* __restrict__ in,
                                      _Float16* __restrict__ out, int ncols) {
  __shared__ float tile[32][33];
  int n0 = blockIdx.x * 32, k0 = blockIdx.y * 32;
  int tx = threadIdx.x, ty = threadIdx.y;
#pragma unroll
  for (int i = 0; i < 32; i += 8)
    tile[ty + i][tx] = in[(size_t)(k0 + ty + i) * ncols + (n0 + tx)];
  __syncthreads();
#pragma unroll
  for (int i = 0; i < 32; i += 8)
    out[(size_t)(n0 + ty + i) * 2048 + (k0 + tx)] = (_Float16)tile[tx][ty + i];
}

// RoPE in-place on Q (heads 0..15) and K (heads 16..19). One thread per
// (m,h): sincos computed ONCE, applied to all 20 heads (was 20x redundant).
// Q heads additionally pre-scaled by log2(e) so attn logits are in log2
// units without per-load scaling in the attn kernel.
__global__ void rope_kernel(_Float16* __restrict__ qkv, const int* __restrict__ pos) {
  int idx = blockIdx.x * 256 + threadIdx.x;   // < 4096*64
  int h = idx & 63;
  int m = idx >> 6;
  float p = (float)pos[m];
  // 10000^(-h/64) = 2^(-h*log2(10000)/64)
  float freq = __builtin_amdgcn_exp2f(-0.2076204747f * (float)h);
  float a = p * freq;
  float s, c;
  sincosf(a, &s, &c);
  const float L = 1.4426950408889634f;
  float cq = c * L, sq = s * L;
  _Float16* base = qkv + (size_t)m * NQKV + h;
#pragma unroll
  for (int head = 0; head < 20; ++head) {
    const bool isq = head < 16;
    _Float16* ptr = isq ? (base + head * H_) : (base + KOFF + (head - 16) * H_);
    float x1 = (float)ptr[0], x2 = (float)ptr[64];
    float cc = isq ? cq : c, ss = isq ? sq : s;
    ptr[0]  = (_Float16)(x1 * cc - x2 * ss);
    ptr[64] = (_Float16)(x2 * cc + x1 * ss);
  }
}

// V section of QKV [m][2560+kh*128+h] -> Vt [b][kh][h][t]
// tile padded to 34: read stride 34 halves -> bank 17*tx mod 32, gcd(17,32)=1.
__global__ void vtrans_kernel(const _Float16* __restrict__ qkv, _Float16* __restrict__ vt) {
  __shared__ _Float16 tile[32][34];
  int t0 = blockIdx.x * 32, h0 = blockIdx.y * 32;
  int slab = blockIdx.z;  // b*4 + kh
  int tx = threadIdx.x, ty = threadIdx.y;
  int b = slab >> 2, kh = slab & 3;
#pragma unroll
  for (int i = 0; i < 32; i += 8)
    tile[ty + i][tx] = qkv[(size_t)(b * T_ + t0 + ty + i) * NQKV + VOFF + kh * H_ + h0 + tx];
  __syncthreads();
#pragma unroll
  for (int i = 0; i < 32; i += 8)
    vt[(size_t)(slab * H_ + h0 + ty + i) * T_ + (t0 + tx)] = tile[tx][ty + i];
}

// ---------------- GEMM: C[M,N] = A[M,K] * Bt[N,K]^T ----------------
// 128x128 tile, BK=64, 4 waves (2x2), 4x4 16x16x32 frags/wave. Proven 875 TF
// (~96% of this structure's 912 TF ceiling); grids 768/512 fill 256 CUs
// exactly. 256-tile variants cannot (192/384-block grids) -- keep 128^2.
// LDS XOR-swizzle (unit ^= row&7) via pre-swizzled global source (rule 21).

template <int OUT_F32>
__global__ __launch_bounds__(256, 2) void gemm_kernel(const _Float16* __restrict__ A,
                                                      const _Float16* __restrict__ Bt,
                                                      void* __restrict__ Cout, int N, int K) {
  __shared__ __align__(16) _Float16 As[128 * 64];
  __shared__ __align__(16) _Float16 Bs[128 * 64];
  const int tid = threadIdx.x;
  const int wave = tid >> 6, lane = tid & 63;
  const int lg = lane >> 4, lm = lane & 15;
  const int brow = blockIdx.y * 128, bcol = blockIdx.x * 128;
  const int wr = wave >> 1, wc = wave & 1;
  f32x4 acc[4][4] = {};
  for (int k0 = 0; k0 < K; k0 += 64) {
#pragma unroll
    for (int j = 0; j < 4; ++j) {
      int U = j * 256 + tid;          // 16B unit index, 8 units/row
      int row = U >> 3, u = U & 7;
      int us = u ^ (row & 7);
      GLOAD16(A + (size_t)(brow + row) * K + k0 + us * 8, (char*)As + ((j * 256 + wave * 64) << 4));
      GLOAD16(Bt + (size_t)(bcol + row) * K + k0 + us * 8, (char*)Bs + ((j * 256 + wave * 64) << 4));
    }
    __syncthreads();
#pragma unroll
    for (int kk = 0; kk < 2; ++kk) {
      half8 af[4], bf[4];
#pragma unroll
      for (int m = 0; m < 4; ++m) {
        int row = wr * 64 + m * 16 + lm;
        int u = (kk * 4 + lg) ^ (row & 7);
        af[m] = *reinterpret_cast<const half8*>(As + row * 64 + u * 8);
      }
#pragma unroll
      for (int n = 0; n < 4; ++n) {
        int row = wc * 64 + n * 16 + lm;
        int u = (kk * 4 + lg) ^ (row & 7);
        bf[n] = *reinterpret_cast<const half8*>(Bs + row * 64 + u * 8);
      }
#pragma unroll
      for (int m = 0; m < 4; ++m)
#pragma unroll
        for (int n = 0; n < 4; ++n)
          acc[m][n] = __builtin_amdgcn_mfma_f32_16x16x32_f16(af[m], bf[n], acc[m][n], 0, 0, 0);
    }
    __syncthreads();
  }
#pragma unroll
  for (int m = 0; m < 4; ++m)
#pragma unroll
    for (int n = 0; n < 4; ++n)
#pragma unroll
      for (int r = 0; r < 4; ++r) {
        size_t row = brow + wr * 64 + m * 16 + lg * 4 + r;
        size_t col = bcol + wc * 64 + n * 16 + lm;
        if constexpr (OUT_F32) ((float*)Cout)[row * N + col] = acc[m][n][r];
        else ((_Float16*)Cout)[row * N + col] = (_Float16)acc[m][n][r];
      }
}

// ---------------- flash attention (round-3/4 best: 72 us) ----------------
// Uniform-work blocks: q-tile = 64 rows (wave owns 16), tiles paired (p, 31-p)
// in-block -> every block exactly 33 KV-iterations. 512 blocks = 2/CU;
// XCD chunk = one (b,kh) K/V set. Double-buffered K/V, counted vmcnt, setprio.
// Swapped QK^T (mfma(K,Q)): lane owns one q-row -> row-reduce = 15 fmax+2 shfl.
// Q pre-scaled by log2e in rope -> raw qf loads. Defer-max THR=14 (log2).

__global__ __launch_bounds__(256, 2) void attn_kernel(const _Float16* __restrict__ qkv,
                                                      const _Float16* __restrict__ vt,
                                                      _Float16* __restrict__ attn) {
  __shared__ __align__(16) _Float16 Ks[2][64 * 128];    // [s][h], 16 units/row, u^= s&15
  __shared__ __align__(16) _Float16 Vs[2][128 * 64];    // [h][s],  8 units/row, u^= h&7
  __shared__ __align__(16) _Float16 Ps[4][16 * 64];     // per-wave [q][s], u^= q&7
  const int bid = blockIdx.x;
  const int swz = (bid & 7) * 64 + (bid >> 3);          // XCD chunk = 64 consecutive swz
  const int chunk = swz >> 6;                           // = b*4 + kh
  const int b = chunk >> 2, kh = chunk & 3;
  const int n = kh * 4 + ((swz >> 4) & 3);
  const int p = swz & 15;                               // pair index
  const int tid = threadIdx.x, wave = tid >> 6, lane = tid & 63;
  const int lg = lane >> 4, lm = lane & 15;

  auto stage = [&](int j, int buf) {
    const int s0 = j * 64;
    char* Kb = (char*)&Ks[buf][0];
    char* Vb = (char*)&Vs[buf][0];
#pragma unroll
    for (int jj = 0; jj < 4; ++jj) {   // K tile: 64 rows x 16 units
      int U = jj * 256 + tid;
      int srow = U >> 4, u = U & 15;
      int us = u ^ (srow & 15);
      GLOAD16(qkv + (size_t)(b * T_ + s0 + srow) * NQKV + KOFF + kh * H_ + us * 8,
              Kb + ((jj * 256 + wave * 64) << 4));
    }
#pragma unroll
    for (int jj = 0; jj < 4; ++jj) {   // Vt tile: 128 rows x 8 units
      int U = jj * 256 + tid;
      int hrow = U >> 3, u = U & 7;
      int us = u ^ (hrow & 7);
      GLOAD16(vt + (size_t)((b * NK_ + kh) * H_ + hrow) * T_ + s0 + us * 8,
              Vb + ((jj * 256 + wave * 64) << 4));
    }
  };

  for (int ph = 0; ph < 2; ++ph) {
    const int t = ph ? (31 - p) : p;                    // q-tile index, rows [64t, 64t+63]
    const int qbase = t * 64 + wave * 16;

    // Q fragments (already scaled by log2e in rope).
    half8 qf[4];
    const _Float16* qptr = qkv + (size_t)(b * T_ + qbase + lm) * NQKV + n * H_;
#pragma unroll
    for (int kk = 0; kk < 4; ++kk)
      qf[kk] = *reinterpret_cast<const half8*>(qptr + kk * 32 + lg * 8);

    f32x4 o[8] = {};
    float mrow_s = -1e30f, lrow_s = 0.f;

    const int nkv = t + 1;
    stage(0, 0);
    for (int it = 0; it < nkv; ++it) {
      const int cur = it & 1;
      if (it + 1 < nkv) { stage(it + 1, cur ^ 1); WAIT_VM8(); }
      else              { WAIT_VM0(); }
      BAR();
      const _Float16* Kt = &Ks[cur][0];
      const _Float16* Vt2 = &Vs[cur][0];

      // Swapped QK^T: S[ns][r] = logit(q = qbase+lm, s = it*64 + ns*16 + lg*4 + r)
      f32x4 S[4];
      __builtin_amdgcn_s_setprio(1);
#pragma unroll
      for (int ns = 0; ns < 4; ++ns) {
        half8 kf[4];
        int srow = ns * 16 + lm;
#pragma unroll
        for (int kk = 0; kk < 4; ++kk) {
          int u = (kk * 4 + lg) ^ (srow & 15);
          kf[kk] = *reinterpret_cast<const half8*>(Kt + srow * 128 + u * 8);
        }
        f32x4 a = {0.f, 0.f, 0.f, 0.f};
#pragma unroll
        for (int kk = 0; kk < 4; ++kk)
          a = __builtin_amdgcn_mfma_f32_16x16x32_f16(kf[kk], qf[kk], a, 0, 0, 0);
        S[ns] = a;
      }
      __builtin_amdgcn_s_setprio(0);

      if (it == t) {                  // diagonal tile: causal mask
        const int q = qbase + lm;
#pragma unroll
        for (int ns = 0; ns < 4; ++ns)
#pragma unroll
          for (int r = 0; r < 4; ++r) {
            int s = t * 64 + ns * 16 + lg * 4 + r;
            if (s > q) S[ns][r] = -1e30f;
          }
      }

      // Row max: 15 local fmax + 2 shfl (lanes xor16/xor32 share the q-row).
      float pm0 = fmaxf(fmaxf(S[0][0], S[0][1]), fmaxf(S[0][2], S[0][3]));
      float pm1 = fmaxf(fmaxf(S[1][0], S[1][1]), fmaxf(S[1][2], S[1][3]));
      float pm2 = fmaxf(fmaxf(S[2][0], S[2][1]), fmaxf(S[2][2], S[2][3]));
      float pm3 = fmaxf(fmaxf(S[3][0], S[3][1]), fmaxf(S[3][2], S[3][3]));
      float pm = fmaxf(fmaxf(pm0, pm1), fmaxf(pm2, pm3));
      pm = fmaxf(pm, __shfl_xor(pm, 16));
      pm = fmaxf(pm, __shfl_xor(pm, 32));

      // Defer-max: only rescale when some row's max grew past THR (log2 units).
      if (__any(pm > mrow_s + 14.f)) {
        float mn = fmaxf(mrow_s, pm);
        float sc = __builtin_amdgcn_exp2f(mrow_s - mn);
        mrow_s = mn;
        lrow_s *= sc;
        float scr[4];
#pragma unroll
        for (int r = 0; r < 4; ++r) scr[r] = __shfl(sc, lg * 4 + r);
#pragma unroll
        for (int nh = 0; nh < 8; ++nh)
#pragma unroll
          for (int r = 0; r < 4; ++r) o[nh][r] *= scr[r];
      }

      const float m = mrow_s;
      float ps = 0.f;
#pragma unroll
      for (int ns = 0; ns < 4; ++ns)
#pragma unroll
        for (int r = 0; r < 4; ++r) {
          float pv = __builtin_amdgcn_exp2f(S[ns][r] - m);
          S[ns][r] = pv;
          ps += pv;
        }
      ps += __shfl_xor(ps, 16);
      ps += __shfl_xor(ps, 32);
      lrow_s += ps;

      // P -> LDS: 4x ds_write_b64 (packed half4), same XOR swizzle as PA read.
#pragma unroll
      for (int ns = 0; ns < 4; ++ns) {
        half4 pk;
#pragma unroll
        for (int r = 0; r < 4; ++r) pk[r] = (_Float16)S[ns][r];
        int u = (2 * ns + (lg >> 1)) ^ (lm & 7);
        *reinterpret_cast<half4*>(&Ps[wave][lm * 64 + u * 8 + (lg & 1) * 4]) = pk;
      }

      __builtin_amdgcn_s_setprio(1);
#pragma unroll
      for (int kk2 = 0; kk2 < 2; ++kk2) {
        int up = (kk2 * 4 + lg) ^ (lm & 7);
        half8 pa = *reinterpret_cast<const half8*>(&Ps[wave][lm * 64 + up * 8]);
#pragma unroll
        for (int nh = 0; nh < 8; ++nh) {
          int hrow = nh * 16 + lm;
          int u = (kk2 * 4 + lg) ^ (hrow & 7);
          half8 vf = *reinterpret_cast<const half8*>(Vt2 + hrow * 64 + u * 8);
          o[nh] = __builtin_amdgcn_mfma_f32_16x16x32_f16(pa, vf, o[nh], 0, 0, 0);
        }
      }
      __builtin_amdgcn_s_setprio(0);
      BAR();
    }

    float linv[4];
#pragma unroll
    for (int r = 0; r < 4; ++r) linv[r] = 1.f / __shfl(lrow_s, lg * 4 + r);
#pragma unroll
    for (int r = 0; r < 4; ++r) {
      int q = qbase + lg * 4 + r;
      _Float16* optr = attn + ((size_t)(b * T_ + q) * NQ_ + n) * H_ + lm;
#pragma unroll
      for (int nh = 0; nh < 8; ++nh)
        optr[nh * 16] = (_Float16)(o[nh][r] * linv[r]);
    }
  }
}

// ---------------- launch ----------------

extern "C" void kernel_launch(void* const* d_in, const int* in_sizes, int n_in,
                              void* d_out, int out_size, void* d_ws, size_t ws_size,
                              hipStream_t stream) {
  const float* X  = (const float*)d_in[0];
  const int* pos  = (const int*)d_in[1];
  const float* Wq = (const float*)d_in[2];
  const float* Wk = (const float*)d_in[3];
  const float* Wv = (const float*)d_in[4];
  const float* Wo = (const float*)d_in[5];

  _Float16* Xh    = (_Float16*)d_ws;                   // 4096*2048
  _Float16* Wqkvt = Xh + (size_t)4096 * 2048;          // [3072][2048]
  _Float16* Wot   = Wqkvt + (size_t)3072 * 2048;       // [2048][2048]
  _Float16* QKV   = Wot + (size_t)2048 * 2048;         // [4096][3072]
  _Float16* Vt    = QKV + (size_t)4096 * 3072;         // [2][4][128][2048]
  _Float16* Attn  = Vt + (size_t)8 * 128 * 2048;       // [4096][2048]

  dim3 tb(32, 8);
  cast_x_kernel<<<8192, 256, 0, stream>>>(X, Xh);
  transpose_cast_kernel<<<dim3(64, 64), tb, 0, stream>>>(Wq, Wqkvt, 2048);
  transpose_cast_kernel<<<dim3(16, 64), tb, 0, stream>>>(Wk, Wqkvt + (size_t)2048 * 2048, 512);
  transpose_cast_kernel<<<dim3(16, 64), tb, 0, stream>>>(Wv, Wqkvt + (size_t)2560 * 2048, 512);
  transpose_cast_kernel<<<dim3(64, 64), tb, 0, stream>>>(Wo, Wot, 2048);

  gemm_kernel<0><<<dim3(24, 32), 256, 0, stream>>>(Xh, Wqkvt, QKV, NQKV, 2048);
  rope_kernel<<<1024, 256, 0, stream>>>(QKV, pos);
  vtrans_kernel<<<dim3(64, 4, 8), tb, 0, stream>>>(QKV, Vt);
  attn_kernel<<<512, 256, 0, stream>>>(QKV, Vt, Attn);
  gemm_kernel<1><<<dim3(16, 32), 256, 0, stream>>>(Attn, Wot, d_out, 2048, 2048);
}

// Round 10
// 200.561 us; speedup vs baseline: 1.1467x; 1.0071x over previous
//
#include <hip/hip_runtime.h>

// Fused: X->QKV proj (fp16 MFMA) -> RoPE -> GQA causal flash attn -> out proj.
// B=2 T=2048 D=2048 NQ=16 NK=4 H=128, scale=1.0 (no 1/sqrt(H)).

typedef _Float16 half8 __attribute__((ext_vector_type(8)));
typedef _Float16 half4 __attribute__((ext_vector_type(4)));
typedef float f32x4 __attribute__((ext_vector_type(4)));

#define GLOAD16(gp, lp) \
  __builtin_amdgcn_global_load_lds((__attribute__((address_space(1))) void*)(gp), \
                                   (__attribute__((address_space(3))) void*)(lp), 16, 0, 0)

#define WAIT_VM8() asm volatile("s_waitcnt vmcnt(8)" ::: "memory")
#define WAIT_VM0() asm volatile("s_waitcnt vmcnt(0)" ::: "memory")
#define BAR() asm volatile("s_barrier" ::: "memory")

static constexpr int T_   = 2048;
static constexpr int D_   = 2048;
static constexpr int NQ_  = 16;
static constexpr int NK_  = 4;
static constexpr int H_   = 128;
static constexpr int NQKV = 3072;   // 16*128 + 4*128 + 4*128
static constexpr int KOFF = 2048;
static constexpr int VOFF = 2560;

// ---------------- prep kernels ----------------

__global__ void cast_x_kernel(const float* __restrict__ in, _Float16* __restrict__ out) {
  int i = (blockIdx.x * 256 + threadIdx.x) * 4;
  float4 v = *reinterpret_cast<const float4*>(in + i);
  union { _Float16 h[4]; uint2 u; } p;
  p.h[0] = (_Float16)v.x; p.h[1] = (_Float16)v.y;
  p.h[2] = (_Float16)v.z; p.h[3] = (_Float16)v.w;
  *reinterpret_cast<uint2*>(out + i) = p.u;
}

// All four weight transposes in one launch (identical geometry; branch on bx).
// in: [2048][ncols] f32 -> out: [ncols][2048] f16 (row stride 2048).
__global__ void transpose_all_kernel(const float* __restrict__ Wq,
                                     const float* __restrict__ Wk,
                                     const float* __restrict__ Wv,
                                     const float* __restrict__ Wo,
                                     _Float16* __restrict__ Wqkvt,
                                     _Float16* __restrict__ Wot) {
  __shared__ float tile[32][33];
  int bx = blockIdx.x;                 // 0..159
  const float* src; _Float16* dst; int ncols, n0;
  if (bx < 64)      { src = Wq; dst = Wqkvt;                      ncols = 2048; n0 = bx * 32; }
  else if (bx < 80) { src = Wk; dst = Wqkvt + (size_t)2048 * 2048; ncols = 512; n0 = (bx - 64) * 32; }
  else if (bx < 96) { src = Wv; dst = Wqkvt + (size_t)2560 * 2048; ncols = 512; n0 = (bx - 80) * 32; }
  else              { src = Wo; dst = Wot;                        ncols = 2048; n0 = (bx - 96) * 32; }
  int k0 = blockIdx.y * 32;
  int tx = threadIdx.x, ty = threadIdx.y;
#pragma unroll
  for (int i = 0; i < 32; i += 8)
    tile[ty + i][tx] = src[(size_t)(k0 + ty + i) * ncols + (n0 + tx)];
  __syncthreads();
#pragma unroll
  for (int i = 0; i < 32; i += 8)
    dst[(size_t)(n0 + ty + i) * 2048 + (k0 + tx)] = (_Float16)tile[tx][ty + i];
}

// RoPE in-place on K heads only (Q rope is folded into the attn Q-load).
// One thread per (m,h): sincos once, applied to 4 K heads.
__global__ void rope_k_kernel(_Float16* __restrict__ qkv, const int* __restrict__ pos) {
  int idx = blockIdx.x * 256 + threadIdx.x;   // < 4096*64
  int h = idx & 63;
  int m = idx >> 6;
  float p = (float)pos[m];
  float freq = __builtin_amdgcn_exp2f(-0.2076204747f * (float)h);  // 10000^(-h/64)
  float a = p * freq;
  float s, c;
  sincosf(a, &s, &c);
  _Float16* base = qkv + (size_t)m * NQKV + KOFF + h;
#pragma unroll
  for (int head = 0; head < 4; ++head) {
    _Float16* ptr = base + head * H_;
    float x1 = (float)ptr[0], x2 = (float)ptr[64];
    ptr[0]  = (_Float16)(x1 * c - x2 * s);
    ptr[64] = (_Float16)(x2 * c + x1 * s);
  }
}

// V section of QKV [m][2560+kh*128+h] -> Vt [b][kh][h][t]
// tile padded to 34: read stride 34 halves -> bank 17*tx mod 32, gcd(17,32)=1.
__global__ void vtrans_kernel(const _Float16* __restrict__ qkv, _Float16* __restrict__ vt) {
  __shared__ _Float16 tile[32][34];
  int t0 = blockIdx.x * 32, h0 = blockIdx.y * 32;
  int slab = blockIdx.z;  // b*4 + kh
  int tx = threadIdx.x, ty = threadIdx.y;
  int b = slab >> 2, kh = slab & 3;
#pragma unroll
  for (int i = 0; i < 32; i += 8)
    tile[ty + i][tx] = qkv[(size_t)(b * T_ + t0 + ty + i) * NQKV + VOFF + kh * H_ + h0 + tx];
  __syncthreads();
#pragma unroll
  for (int i = 0; i < 32; i += 8)
    vt[(size_t)(slab * H_ + h0 + ty + i) * T_ + (t0 + tx)] = tile[tx][ty + i];
}

// ---------------- GEMM: C[M,N] = A[M,K] * Bt[N,K]^T ----------------
// 128x128 tile, BK=64, 4 waves (2x2), 4x4 16x16x32 frags/wave. Proven 875 TF
// (~96% of this structure's 912 TF ceiling); grids 768/512 fill 256 CUs.
// LDS XOR-swizzle (unit ^= row&7) via pre-swizzled global source (rule 21).

template <int OUT_F32>
__global__ __launch_bounds__(256, 2) void gemm_kernel(const _Float16* __restrict__ A,
                                                      const _Float16* __restrict__ Bt,
                                                      void* __restrict__ Cout, int N, int K) {
  __shared__ __align__(16) _Float16 As[128 * 64];
  __shared__ __align__(16) _Float16 Bs[128 * 64];
  const int tid = threadIdx.x;
  const int wave = tid >> 6, lane = tid & 63;
  const int lg = lane >> 4, lm = lane & 15;
  const int brow = blockIdx.y * 128, bcol = blockIdx.x * 128;
  const int wr = wave >> 1, wc = wave & 1;
  f32x4 acc[4][4] = {};
  for (int k0 = 0; k0 < K; k0 += 64) {
#pragma unroll
    for (int j = 0; j < 4; ++j) {
      int U = j * 256 + tid;          // 16B unit index, 8 units/row
      int row = U >> 3, u = U & 7;
      int us = u ^ (row & 7);
      GLOAD16(A + (size_t)(brow + row) * K + k0 + us * 8, (char*)As + ((j * 256 + wave * 64) << 4));
      GLOAD16(Bt + (size_t)(bcol + row) * K + k0 + us * 8, (char*)Bs + ((j * 256 + wave * 64) << 4));
    }
    __syncthreads();
#pragma unroll
    for (int kk = 0; kk < 2; ++kk) {
      half8 af[4], bf[4];
#pragma unroll
      for (int m = 0; m < 4; ++m) {
        int row = wr * 64 + m * 16 + lm;
        int u = (kk * 4 + lg) ^ (row & 7);
        af[m] = *reinterpret_cast<const half8*>(As + row * 64 + u * 8);
      }
#pragma unroll
      for (int n = 0; n < 4; ++n) {
        int row = wc * 64 + n * 16 + lm;
        int u = (kk * 4 + lg) ^ (row & 7);
        bf[n] = *reinterpret_cast<const half8*>(Bs + row * 64 + u * 8);
      }
#pragma unroll
      for (int m = 0; m < 4; ++m)
#pragma unroll
        for (int n = 0; n < 4; ++n)
          acc[m][n] = __builtin_amdgcn_mfma_f32_16x16x32_f16(af[m], bf[n], acc[m][n], 0, 0, 0);
    }
    __syncthreads();
  }
#pragma unroll
  for (int m = 0; m < 4; ++m)
#pragma unroll
    for (int n = 0; n < 4; ++n)
#pragma unroll
      for (int r = 0; r < 4; ++r) {
        size_t row = brow + wr * 64 + m * 16 + lg * 4 + r;
        size_t col = bcol + wc * 64 + n * 16 + lm;
        if constexpr (OUT_F32) ((float*)Cout)[row * N + col] = acc[m][n][r];
        else ((_Float16*)Cout)[row * N + col] = (_Float16)acc[m][n][r];
      }
}

// ---------------- flash attention ----------------
// Uniform-work blocks: q-tile = 64 rows (wave owns 16), tiles paired (p, 31-p)
// in-block -> every block exactly 33 KV-iterations. 512 blocks = 2/CU;
// XCD chunk = one (b,kh) K/V set. Double-buffered K/V, counted vmcnt, setprio.
// Swapped QK^T (mfma(K,Q)): lane owns one q-row -> row-reduce = 15 fmax+2 shfl.
// Q-RoPE applied in-register at load (Q rows read exactly once), log2e folded.
// Defer-max THR=14 (log2 units).

__global__ __launch_bounds__(256, 2) void attn_kernel(const _Float16* __restrict__ qkv,
                                                      const _Float16* __restrict__ vt,
                                                      const int* __restrict__ pos,
                                                      _Float16* __restrict__ attn) {
  __shared__ __align__(16) _Float16 Ks[2][64 * 128];    // [s][h], 16 units/row, u^= s&15
  __shared__ __align__(16) _Float16 Vs[2][128 * 64];    // [h][s],  8 units/row, u^= h&7
  __shared__ __align__(16) _Float16 Ps[4][16 * 64];     // per-wave [q][s], u^= q&7
  const int bid = blockIdx.x;
  const int swz = (bid & 7) * 64 + (bid >> 3);          // XCD chunk = 64 consecutive swz
  const int chunk = swz >> 6;                           // = b*4 + kh
  const int b = chunk >> 2, kh = chunk & 3;
  const int n = kh * 4 + ((swz >> 4) & 3);
  const int p = swz & 15;                               // pair index
  const int tid = threadIdx.x, wave = tid >> 6, lane = tid & 63;
  const int lg = lane >> 4, lm = lane & 15;

  auto stage = [&](int j, int buf) {
    const int s0 = j * 64;
    char* Kb = (char*)&Ks[buf][0];
    char* Vb = (char*)&Vs[buf][0];
#pragma unroll
    for (int jj = 0; jj < 4; ++jj) {   // K tile: 64 rows x 16 units
      int U = jj * 256 + tid;
      int srow = U >> 4, u = U & 15;
      int us = u ^ (srow & 15);
      GLOAD16(qkv + (size_t)(b * T_ + s0 + srow) * NQKV + KOFF + kh * H_ + us * 8,
              Kb + ((jj * 256 + wave * 64) << 4));
    }
#pragma unroll
    for (int jj = 0; jj < 4; ++jj) {   // Vt tile: 128 rows x 8 units
      int U = jj * 256 + tid;
      int hrow = U >> 3, u = U & 7;
      int us = u ^ (hrow & 7);
      GLOAD16(vt + (size_t)((b * NK_ + kh) * H_ + hrow) * T_ + s0 + us * 8,
              Vb + ((jj * 256 + wave * 64) << 4));
    }
  };

  for (int ph = 0; ph < 2; ++ph) {
    const int t = ph ? (31 - p) : p;                    // q-tile index, rows [64t, 64t+63]
    const int qbase = t * 64 + wave * 16;

    // Q fragments: raw load + in-register RoPE + log2e fold.
    // qf[kk][j] holds Q[row][h = kk*32+lg*8+j] for kk<2 (h<64) and h+64 for kk+2.
    half8 qf[4];
    {
      const _Float16* qptr = qkv + (size_t)(b * T_ + qbase + lm) * NQKV + n * H_;
      const float pq = (float)pos[b * T_ + qbase + lm];
      half8 qlo[2], qhi[2];
#pragma unroll
      for (int kk = 0; kk < 2; ++kk) {
        qlo[kk] = *reinterpret_cast<const half8*>(qptr + kk * 32 + lg * 8);
        qhi[kk] = *reinterpret_cast<const half8*>(qptr + 64 + kk * 32 + lg * 8);
      }
      const float L = 1.4426950408889634f;
#pragma unroll
      for (int kk = 0; kk < 2; ++kk)
#pragma unroll
        for (int j = 0; j < 8; ++j) {
          int h = kk * 32 + lg * 8 + j;
          float freq = __builtin_amdgcn_exp2f(-0.2076204747f * (float)h);
          float a = pq * freq;
          float s, c;
          sincosf(a, &s, &c);
          float x1 = (float)qlo[kk][j], x2 = (float)qhi[kk][j];
          qf[kk][j]     = (_Float16)((x1 * c - x2 * s) * L);
          qf[kk + 2][j] = (_Float16)((x2 * c + x1 * s) * L);
        }
    }

    f32x4 o[8] = {};
    float mrow_s = -1e30f, lrow_s = 0.f;

    const int nkv = t + 1;
    stage(0, 0);
    for (int it = 0; it < nkv; ++it) {
      const int cur = it & 1;
      if (it + 1 < nkv) { stage(it + 1, cur ^ 1); WAIT_VM8(); }
      else              { WAIT_VM0(); }
      BAR();
      const _Float16* Kt = &Ks[cur][0];
      const _Float16* Vt2 = &Vs[cur][0];

      // Swapped QK^T: S[ns][r] = logit(q = qbase+lm, s = it*64 + ns*16 + lg*4 + r)
      f32x4 S[4];
      __builtin_amdgcn_s_setprio(1);
#pragma unroll
      for (int ns = 0; ns < 4; ++ns) {
        half8 kf[4];
        int srow = ns * 16 + lm;
#pragma unroll
        for (int kk = 0; kk < 4; ++kk) {
          int u = (kk * 4 + lg) ^ (srow & 15);
          kf[kk] = *reinterpret_cast<const half8*>(Kt + srow * 128 + u * 8);
        }
        f32x4 a = {0.f, 0.f, 0.f, 0.f};
#pragma unroll
        for (int kk = 0; kk < 4; ++kk)
          a = __builtin_amdgcn_mfma_f32_16x16x32_f16(kf[kk], qf[kk], a, 0, 0, 0);
        S[ns] = a;
      }
      __builtin_amdgcn_s_setprio(0);

      if (it == t) {                  // diagonal tile: causal mask
        const int q = qbase + lm;
#pragma unroll
        for (int ns = 0; ns < 4; ++ns)
#pragma unroll
          for (int r = 0; r < 4; ++r) {
            int s = t * 64 + ns * 16 + lg * 4 + r;
            if (s > q) S[ns][r] = -1e30f;
          }
      }

      // Row max: 15 local fmax + 2 shfl (lanes xor16/xor32 share the q-row).
      float pm0 = fmaxf(fmaxf(S[0][0], S[0][1]), fmaxf(S[0][2], S[0][3]));
      float pm1 = fmaxf(fmaxf(S[1][0], S[1][1]), fmaxf(S[1][2], S[1][3]));
      float pm2 = fmaxf(fmaxf(S[2][0], S[2][1]), fmaxf(S[2][2], S[2][3]));
      float pm3 = fmaxf(fmaxf(S[3][0], S[3][1]), fmaxf(S[3][2], S[3][3]));
      float pm = fmaxf(fmaxf(pm0, pm1), fmaxf(pm2, pm3));
      pm = fmaxf(pm, __shfl_xor(pm, 16));
      pm = fmaxf(pm, __shfl_xor(pm, 32));

      // Defer-max: only rescale when some row's max grew past THR (log2 units).
      if (__any(pm > mrow_s + 14.f)) {
        float mn = fmaxf(mrow_s, pm);
        float sc = __builtin_amdgcn_exp2f(mrow_s - mn);
        mrow_s = mn;
        lrow_s *= sc;
        float scr[4];
#pragma unroll
        for (int r = 0; r < 4; ++r) scr[r] = __shfl(sc, lg * 4 + r);
#pragma unroll
        for (int nh = 0; nh < 8; ++nh)
#pragma unroll
          for (int r = 0; r < 4; ++r) o[nh][r] *= scr[r];
      }

      const float m = mrow_s;
      float ps = 0.f;
#pragma unroll
      for (int ns = 0; ns < 4; ++ns)
#pragma unroll
        for (int r = 0; r < 4; ++r) {
          float pv = __builtin_amdgcn_exp2f(S[ns][r] - m);
          S[ns][r] = pv;
          ps += pv;
        }
      ps += __shfl_xor(ps, 16);
      ps += __shfl_xor(ps, 32);
      lrow_s += ps;

      // P -> LDS: 4x ds_write_b64 (packed half4), same XOR swizzle as PA read.
#pragma unroll
      for (int ns = 0; ns < 4; ++ns) {
        half4 pk;
#pragma unroll
        for (int r = 0; r < 4; ++r) pk[r] = (_Float16)S[ns][r];
        int u = (2 * ns + (lg >> 1)) ^ (lm & 7);
        *reinterpret_cast<half4*>(&Ps[wave][lm * 64 + u * 8 + (lg & 1) * 4]) = pk;
      }

      __builtin_amdgcn_s_setprio(1);
#pragma unroll
      for (int kk2 = 0; kk2 < 2; ++kk2) {
        int up = (kk2 * 4 + lg) ^ (lm & 7);
        half8 pa = *reinterpret_cast<const half8*>(&Ps[wave][lm * 64 + up * 8]);
#pragma unroll
        for (int nh = 0; nh < 8; ++nh) {
          int hrow = nh * 16 + lm;
          int u = (kk2 * 4 + lg) ^ (hrow & 7);
          half8 vf = *reinterpret_cast<const half8*>(Vt2 + hrow * 64 + u * 8);
          o[nh] = __builtin_amdgcn_mfma_f32_16x16x32_f16(pa, vf, o[nh], 0, 0, 0);
        }
      }
      __builtin_amdgcn_s_setprio(0);
      BAR();
    }

    float linv[4];
#pragma unroll
    for (int r = 0; r < 4; ++r) linv[r] = 1.f / __shfl(lrow_s, lg * 4 + r);
#pragma unroll
    for (int r = 0; r < 4; ++r) {
      int q = qbase + lg * 4 + r;
      _Float16* optr = attn + ((size_t)(b * T_ + q) * NQ_ + n) * H_ + lm;
#pragma unroll
      for (int nh = 0; nh < 8; ++nh)
        optr[nh * 16] = (_Float16)(o[nh][r] * linv[r]);
    }
  }
}

// ---------------- launch ----------------

extern "C" void kernel_launch(void* const* d_in, const int* in_sizes, int n_in,
                              void* d_out, int out_size, void* d_ws, size_t ws_size,
                              hipStream_t stream) {
  const float* X  = (const float*)d_in[0];
  const int* pos  = (const int*)d_in[1];
  const float* Wq = (const float*)d_in[2];
  const float* Wk = (const float*)d_in[3];
  const float* Wv = (const float*)d_in[4];
  const float* Wo = (const float*)d_in[5];

  _Float16* Xh    = (_Float16*)d_ws;                   // 4096*2048
  _Float16* Wqkvt = Xh + (size_t)4096 * 2048;          // [3072][2048]
  _Float16* Wot   = Wqkvt + (size_t)3072 * 2048;       // [2048][2048]
  _Float16* QKV   = Wot + (size_t)2048 * 2048;         // [4096][3072]
  _Float16* Vt    = QKV + (size_t)4096 * 3072;         // [2][4][128][2048]
  _Float16* Attn  = Vt + (size_t)8 * 128 * 2048;       // [4096][2048]

  dim3 tb(32, 8);
  cast_x_kernel<<<8192, 256, 0, stream>>>(X, Xh);
  transpose_all_kernel<<<dim3(160, 64), tb, 0, stream>>>(Wq, Wk, Wv, Wo, Wqkvt, Wot);

  gemm_kernel<0><<<dim3(24, 32), 256, 0, stream>>>(Xh, Wqkvt, QKV, NQKV, 2048);
  rope_k_kernel<<<1024, 256, 0, stream>>>(QKV, pos);
  vtrans_kernel<<<dim3(64, 4, 8), tb, 0, stream>>>(QKV, Vt);
  attn_kernel<<<512, 256, 0, stream>>>(QKV, Vt, pos, Attn);
  gemm_kernel<1><<<dim3(16, 32), 256, 0, stream>>>(Attn, Wot, d_out, 2048, 2048);
}

// Round 11
// 198.273 us; speedup vs baseline: 1.1600x; 1.0115x over previous
//
#include <hip/hip_runtime.h>

// Fused: X->QKV proj (fp16 MFMA) -> RoPE -> GQA causal flash attn -> out proj.
// B=2 T=2048 D=2048 NQ=16 NK=4 H=128, scale=1.0 (no 1/sqrt(H)).

typedef _Float16 half8 __attribute__((ext_vector_type(8)));
typedef _Float16 half4 __attribute__((ext_vector_type(4)));
typedef float f32x4 __attribute__((ext_vector_type(4)));

#define GLOAD16(gp, lp) \
  __builtin_amdgcn_global_load_lds((__attribute__((address_space(1))) void*)(gp), \
                                   (__attribute__((address_space(3))) void*)(lp), 16, 0, 0)

#define WAIT_VM8() asm volatile("s_waitcnt vmcnt(8)" ::: "memory")
#define WAIT_VM0() asm volatile("s_waitcnt vmcnt(0)" ::: "memory")
#define BAR() asm volatile("s_barrier" ::: "memory")

static constexpr int T_   = 2048;
static constexpr int D_   = 2048;
static constexpr int NQ_  = 16;
static constexpr int NK_  = 4;
static constexpr int H_   = 128;
static constexpr int NQKV = 3072;   // 16*128 + 4*128 + 4*128
static constexpr int KOFF = 2048;
static constexpr int VOFF = 2560;

// ---------------- prep kernels ----------------

__global__ void cast_x_kernel(const float* __restrict__ in, _Float16* __restrict__ out) {
  int i = (blockIdx.x * 256 + threadIdx.x) * 4;
  float4 v = *reinterpret_cast<const float4*>(in + i);
  union { _Float16 h[4]; uint2 u; } p;
  p.h[0] = (_Float16)v.x; p.h[1] = (_Float16)v.y;
  p.h[2] = (_Float16)v.z; p.h[3] = (_Float16)v.w;
  *reinterpret_cast<uint2*>(out + i) = p.u;
}

// All four weight transposes in one launch (identical geometry; branch on bx).
// in: [2048][ncols] f32 -> out: [ncols][2048] f16 (row stride 2048).
__global__ void transpose_all_kernel(const float* __restrict__ Wq,
                                     const float* __restrict__ Wk,
                                     const float* __restrict__ Wv,
                                     const float* __restrict__ Wo,
                                     _Float16* __restrict__ Wqkvt,
                                     _Float16* __restrict__ Wot) {
  __shared__ float tile[32][33];
  int bx = blockIdx.x;                 // 0..159
  const float* src; _Float16* dst; int ncols, n0;
  if (bx < 64)      { src = Wq; dst = Wqkvt;                      ncols = 2048; n0 = bx * 32; }
  else if (bx < 80) { src = Wk; dst = Wqkvt + (size_t)2048 * 2048; ncols = 512; n0 = (bx - 64) * 32; }
  else if (bx < 96) { src = Wv; dst = Wqkvt + (size_t)2560 * 2048; ncols = 512; n0 = (bx - 80) * 32; }
  else              { src = Wo; dst = Wot;                        ncols = 2048; n0 = (bx - 96) * 32; }
  int k0 = blockIdx.y * 32;
  int tx = threadIdx.x, ty = threadIdx.y;
#pragma unroll
  for (int i = 0; i < 32; i += 8)
    tile[ty + i][tx] = src[(size_t)(k0 + ty + i) * ncols + (n0 + tx)];
  __syncthreads();
#pragma unroll
  for (int i = 0; i < 32; i += 8)
    dst[(size_t)(n0 + ty + i) * 2048 + (k0 + tx)] = (_Float16)tile[tx][ty + i];
}

// RoPE in-place on Q (heads 0..15) and K (heads 16..19). One thread per
// (m,h): sincos computed ONCE, applied to all 20 heads. Q heads additionally
// pre-scaled by log2(e) so attn logits are in log2 units with raw Q loads.
__global__ void rope_kernel(_Float16* __restrict__ qkv, const int* __restrict__ pos) {
  int idx = blockIdx.x * 256 + threadIdx.x;   // < 4096*64
  int h = idx & 63;
  int m = idx >> 6;
  float p = (float)pos[m];
  float freq = __builtin_amdgcn_exp2f(-0.2076204747f * (float)h);  // 10000^(-h/64)
  float a = p * freq;
  float s, c;
  sincosf(a, &s, &c);
  const float L = 1.4426950408889634f;
  float cq = c * L, sq = s * L;
  _Float16* base = qkv + (size_t)m * NQKV + h;
#pragma unroll
  for (int head = 0; head < 20; ++head) {
    const bool isq = head < 16;
    _Float16* ptr = isq ? (base + head * H_) : (base + KOFF + (head - 16) * H_);
    float x1 = (float)ptr[0], x2 = (float)ptr[64];
    float cc = isq ? cq : c, ss = isq ? sq : s;
    ptr[0]  = (_Float16)(x1 * cc - x2 * ss);
    ptr[64] = (_Float16)(x2 * cc + x1 * ss);
  }
}

// V section of QKV [m][2560+kh*128+h] -> Vt [b][kh][h][t]
// tile padded to 34: read stride 34 halves -> bank 17*tx mod 32, gcd(17,32)=1.
__global__ void vtrans_kernel(const _Float16* __restrict__ qkv, _Float16* __restrict__ vt) {
  __shared__ _Float16 tile[32][34];
  int t0 = blockIdx.x * 32, h0 = blockIdx.y * 32;
  int slab = blockIdx.z;  // b*4 + kh
  int tx = threadIdx.x, ty = threadIdx.y;
  int b = slab >> 2, kh = slab & 3;
#pragma unroll
  for (int i = 0; i < 32; i += 8)
    tile[ty + i][tx] = qkv[(size_t)(b * T_ + t0 + ty + i) * NQKV + VOFF + kh * H_ + h0 + tx];
  __syncthreads();
#pragma unroll
  for (int i = 0; i < 32; i += 8)
    vt[(size_t)(slab * H_ + h0 + ty + i) * T_ + (t0 + tx)] = tile[tx][ty + i];
}

// ---------------- GEMM: C[M,N] = A[M,K] * Bt[N,K]^T ----------------
// 128x128 tile, BK=64, 4 waves (2x2), 4x4 16x16x32 frags/wave. Proven 875 TF
// (~96% of this structure's 912 TF ceiling); grids 768/512 fill 256 CUs.
// LDS XOR-swizzle (unit ^= row&7) via pre-swizzled global source (rule 21).

template <int OUT_F32>
__global__ __launch_bounds__(256, 2) void gemm_kernel(const _Float16* __restrict__ A,
                                                      const _Float16* __restrict__ Bt,
                                                      void* __restrict__ Cout, int N, int K) {
  __shared__ __align__(16) _Float16 As[128 * 64];
  __shared__ __align__(16) _Float16 Bs[128 * 64];
  const int tid = threadIdx.x;
  const int wave = tid >> 6, lane = tid & 63;
  const int lg = lane >> 4, lm = lane & 15;
  const int brow = blockIdx.y * 128, bcol = blockIdx.x * 128;
  const int wr = wave >> 1, wc = wave & 1;
  f32x4 acc[4][4] = {};
  for (int k0 = 0; k0 < K; k0 += 64) {
#pragma unroll
    for (int j = 0; j < 4; ++j) {
      int U = j * 256 + tid;          // 16B unit index, 8 units/row
      int row = U >> 3, u = U & 7;
      int us = u ^ (row & 7);
      GLOAD16(A + (size_t)(brow + row) * K + k0 + us * 8, (char*)As + ((j * 256 + wave * 64) << 4));
      GLOAD16(Bt + (size_t)(bcol + row) * K + k0 + us * 8, (char*)Bs + ((j * 256 + wave * 64) << 4));
    }
    __syncthreads();
#pragma unroll
    for (int kk = 0; kk < 2; ++kk) {
      half8 af[4], bf[4];
#pragma unroll
      for (int m = 0; m < 4; ++m) {
        int row = wr * 64 + m * 16 + lm;
        int u = (kk * 4 + lg) ^ (row & 7);
        af[m] = *reinterpret_cast<const half8*>(As + row * 64 + u * 8);
      }
#pragma unroll
      for (int n = 0; n < 4; ++n) {
        int row = wc * 64 + n * 16 + lm;
        int u = (kk * 4 + lg) ^ (row & 7);
        bf[n] = *reinterpret_cast<const half8*>(Bs + row * 64 + u * 8);
      }
#pragma unroll
      for (int m = 0; m < 4; ++m)
#pragma unroll
        for (int n = 0; n < 4; ++n)
          acc[m][n] = __builtin_amdgcn_mfma_f32_16x16x32_f16(af[m], bf[n], acc[m][n], 0, 0, 0);
    }
    __syncthreads();
  }
#pragma unroll
  for (int m = 0; m < 4; ++m)
#pragma unroll
    for (int n = 0; n < 4; ++n)
#pragma unroll
      for (int r = 0; r < 4; ++r) {
        size_t row = brow + wr * 64 + m * 16 + lg * 4 + r;
        size_t col = bcol + wc * 64 + n * 16 + lm;
        if constexpr (OUT_F32) ((float*)Cout)[row * N + col] = acc[m][n][r];
        else ((_Float16*)Cout)[row * N + col] = (_Float16)acc[m][n][r];
      }
}

// ---------------- flash attention (proven 72 us variant) ----------------
// Uniform-work blocks: q-tile = 64 rows (wave owns 16), tiles paired (p, 31-p)
// in-block -> every block exactly 33 KV-iterations. 512 blocks = 2/CU;
// XCD chunk = one (b,kh) K/V set. Double-buffered K/V, counted vmcnt, setprio.
// Swapped QK^T (mfma(K,Q)): lane owns one q-row -> row-reduce = 15 fmax+2 shfl.
// Q pre-scaled by log2e in rope -> raw qf loads. Defer-max THR=14 (log2).

__global__ __launch_bounds__(256, 2) void attn_kernel(const _Float16* __restrict__ qkv,
                                                      const _Float16* __restrict__ vt,
                                                      _Float16* __restrict__ attn) {
  __shared__ __align__(16) _Float16 Ks[2][64 * 128];    // [s][h], 16 units/row, u^= s&15
  __shared__ __align__(16) _Float16 Vs[2][128 * 64];    // [h][s],  8 units/row, u^= h&7
  __shared__ __align__(16) _Float16 Ps[4][16 * 64];     // per-wave [q][s], u^= q&7
  const int bid = blockIdx.x;
  const int swz = (bid & 7) * 64 + (bid >> 3);          // XCD chunk = 64 consecutive swz
  const int chunk = swz >> 6;                           // = b*4 + kh
  const int b = chunk >> 2, kh = chunk & 3;
  const int n = kh * 4 + ((swz >> 4) & 3);
  const int p = swz & 15;                               // pair index
  const int tid = threadIdx.x, wave = tid >> 6, lane = tid & 63;
  const int lg = lane >> 4, lm = lane & 15;

  auto stage = [&](int j, int buf) {
    const int s0 = j * 64;
    char* Kb = (char*)&Ks[buf][0];
    char* Vb = (char*)&Vs[buf][0];
#pragma unroll
    for (int jj = 0; jj < 4; ++jj) {   // K tile: 64 rows x 16 units
      int U = jj * 256 + tid;
      int srow = U >> 4, u = U & 15;
      int us = u ^ (srow & 15);
      GLOAD16(qkv + (size_t)(b * T_ + s0 + srow) * NQKV + KOFF + kh * H_ + us * 8,
              Kb + ((jj * 256 + wave * 64) << 4));
    }
#pragma unroll
    for (int jj = 0; jj < 4; ++jj) {   // Vt tile: 128 rows x 8 units
      int U = jj * 256 + tid;
      int hrow = U >> 3, u = U & 7;
      int us = u ^ (hrow & 7);
      GLOAD16(vt + (size_t)((b * NK_ + kh) * H_ + hrow) * T_ + s0 + us * 8,
              Vb + ((jj * 256 + wave * 64) << 4));
    }
  };

  for (int ph = 0; ph < 2; ++ph) {
    const int t = ph ? (31 - p) : p;                    // q-tile index, rows [64t, 64t+63]
    const int qbase = t * 64 + wave * 16;

    // Q fragments (already scaled by log2e in rope).
    half8 qf[4];
    const _Float16* qptr = qkv + (size_t)(b * T_ + qbase + lm) * NQKV + n * H_;
#pragma unroll
    for (int kk = 0; kk < 4; ++kk)
      qf[kk] = *reinterpret_cast<const half8*>(qptr + kk * 32 + lg * 8);

    f32x4 o[8] = {};
    float mrow_s = -1e30f, lrow_s = 0.f;

    const int nkv = t + 1;
    stage(0, 0);
    for (int it = 0; it < nkv; ++it) {
      const int cur = it & 1;
      if (it + 1 < nkv) { stage(it + 1, cur ^ 1); WAIT_VM8(); }
      else              { WAIT_VM0(); }
      BAR();
      const _Float16* Kt = &Ks[cur][0];
      const _Float16* Vt2 = &Vs[cur][0];

      // Swapped QK^T: S[ns][r] = logit(q = qbase+lm, s = it*64 + ns*16 + lg*4 + r)
      f32x4 S[4];
      __builtin_amdgcn_s_setprio(1);
#pragma unroll
      for (int ns = 0; ns < 4; ++ns) {
        half8 kf[4];
        int srow = ns * 16 + lm;
#pragma unroll
        for (int kk = 0; kk < 4; ++kk) {
          int u = (kk * 4 + lg) ^ (srow & 15);
          kf[kk] = *reinterpret_cast<const half8*>(Kt + srow * 128 + u * 8);
        }
        f32x4 a = {0.f, 0.f, 0.f, 0.f};
#pragma unroll
        for (int kk = 0; kk < 4; ++kk)
          a = __builtin_amdgcn_mfma_f32_16x16x32_f16(kf[kk], qf[kk], a, 0, 0, 0);
        S[ns] = a;
      }
      __builtin_amdgcn_s_setprio(0);

      if (it == t) {                  // diagonal tile: causal mask
        const int q = qbase + lm;
#pragma unroll
        for (int ns = 0; ns < 4; ++ns)
#pragma unroll
          for (int r = 0; r < 4; ++r) {
            int s = t * 64 + ns * 16 + lg * 4 + r;
            if (s > q) S[ns][r] = -1e30f;
          }
      }

      // Row max: 15 local fmax + 2 shfl (lanes xor16/xor32 share the q-row).
      float pm0 = fmaxf(fmaxf(S[0][0], S[0][1]), fmaxf(S[0][2], S[0][3]));
      float pm1 = fmaxf(fmaxf(S[1][0], S[1][1]), fmaxf(S[1][2], S[1][3]));
      float pm2 = fmaxf(fmaxf(S[2][0], S[2][1]), fmaxf(S[2][2], S[2][3]));
      float pm3 = fmaxf(fmaxf(S[3][0], S[3][1]), fmaxf(S[3][2], S[3][3]));
      float pm = fmaxf(fmaxf(pm0, pm1), fmaxf(pm2, pm3));
      pm = fmaxf(pm, __shfl_xor(pm, 16));
      pm = fmaxf(pm, __shfl_xor(pm, 32));

      // Defer-max: only rescale when some row's max grew past THR (log2 units).
      if (__any(pm > mrow_s + 14.f)) {
        float mn = fmaxf(mrow_s, pm);
        float sc = __builtin_amdgcn_exp2f(mrow_s - mn);
        mrow_s = mn;
        lrow_s *= sc;
        float scr[4];
#pragma unroll
        for (int r = 0; r < 4; ++r) scr[r] = __shfl(sc, lg * 4 + r);
#pragma unroll
        for (int nh = 0; nh < 8; ++nh)
#pragma unroll
          for (int r = 0; r < 4; ++r) o[nh][r] *= scr[r];
      }

      const float m = mrow_s;
      float ps = 0.f;
#pragma unroll
      for (int ns = 0; ns < 4; ++ns)
#pragma unroll
        for (int r = 0; r < 4; ++r) {
          float pv = __builtin_amdgcn_exp2f(S[ns][r] - m);
          S[ns][r] = pv;
          ps += pv;
        }
      ps += __shfl_xor(ps, 16);
      ps += __shfl_xor(ps, 32);
      lrow_s += ps;

      // P -> LDS: 4x ds_write_b64 (packed half4), same XOR swizzle as PA read.
#pragma unroll
      for (int ns = 0; ns < 4; ++ns) {
        half4 pk;
#pragma unroll
        for (int r = 0; r < 4; ++r) pk[r] = (_Float16)S[ns][r];
        int u = (2 * ns + (lg >> 1)) ^ (lm & 7);
        *reinterpret_cast<half4*>(&Ps[wave][lm * 64 + u * 8 + (lg & 1) * 4]) = pk;
      }

      __builtin_amdgcn_s_setprio(1);
#pragma unroll
      for (int kk2 = 0; kk2 < 2; ++kk2) {
        int up = (kk2 * 4 + lg) ^ (lm & 7);
        half8 pa = *reinterpret_cast<const half8*>(&Ps[wave][lm * 64 + up * 8]);
#pragma unroll
        for (int nh = 0; nh < 8; ++nh) {
          int hrow = nh * 16 + lm;
          int u = (kk2 * 4 + lg) ^ (hrow & 7);
          half8 vf = *reinterpret_cast<const half8*>(Vt2 + hrow * 64 + u * 8);
          o[nh] = __builtin_amdgcn_mfma_f32_16x16x32_f16(pa, vf, o[nh], 0, 0, 0);
        }
      }
      __builtin_amdgcn_s_setprio(0);
      BAR();
    }

    float linv[4];
#pragma unroll
    for (int r = 0; r < 4; ++r) linv[r] = 1.f / __shfl(lrow_s, lg * 4 + r);
#pragma unroll
    for (int r = 0; r < 4; ++r) {
      int q = qbase + lg * 4 + r;
      _Float16* optr = attn + ((size_t)(b * T_ + q) * NQ_ + n) * H_ + lm;
#pragma unroll
      for (int nh = 0; nh < 8; ++nh)
        optr[nh * 16] = (_Float16)(o[nh][r] * linv[r]);
    }
  }
}

// ---------------- launch ----------------

extern "C" void kernel_launch(void* const* d_in, const int* in_sizes, int n_in,
                              void* d_out, int out_size, void* d_ws, size_t ws_size,
                              hipStream_t stream) {
  const float* X  = (const float*)d_in[0];
  const int* pos  = (const int*)d_in[1];
  const float* Wq = (const float*)d_in[2];
  const float* Wk = (const float*)d_in[3];
  const float* Wv = (const float*)d_in[4];
  const float* Wo = (const float*)d_in[5];

  _Float16* Xh    = (_Float16*)d_ws;                   // 4096*2048
  _Float16* Wqkvt = Xh + (size_t)4096 * 2048;          // [3072][2048]
  _Float16* Wot   = Wqkvt + (size_t)3072 * 2048;       // [2048][2048]
  _Float16* QKV   = Wot + (size_t)2048 * 2048;         // [4096][3072]
  _Float16* Vt    = QKV + (size_t)4096 * 3072;         // [2][4][128][2048]
  _Float16* Attn  = Vt + (size_t)8 * 128 * 2048;       // [4096][2048]

  dim3 tb(32, 8);
  cast_x_kernel<<<8192, 256, 0, stream>>>(X, Xh);
  transpose_all_kernel<<<dim3(160, 64), tb, 0, stream>>>(Wq, Wk, Wv, Wo, Wqkvt, Wot);

  gemm_kernel<0><<<dim3(24, 32), 256, 0, stream>>>(Xh, Wqkvt, QKV, NQKV, 2048);
  rope_kernel<<<1024, 256, 0, stream>>>(QKV, pos);
  vtrans_kernel<<<dim3(64, 4, 8), tb, 0, stream>>>(QKV, Vt);
  attn_kernel<<<512, 256, 0, stream>>>(QKV, Vt, Attn);
  gemm_kernel<1><<<dim3(16, 32), 256, 0, stream>>>(Attn, Wot, d_out, 2048, 2048);
}

// Round 12
// 196.382 us; speedup vs baseline: 1.1711x; 1.0096x over previous
//
#include <hip/hip_runtime.h>

// Fused: X->QKV proj (fp16 MFMA) -> RoPE -> GQA causal flash attn -> out proj.
// B=2 T=2048 D=2048 NQ=16 NK=4 H=128, scale=1.0 (no 1/sqrt(H)).

typedef _Float16 half8 __attribute__((ext_vector_type(8)));
typedef _Float16 half4 __attribute__((ext_vector_type(4)));
typedef float f32x4 __attribute__((ext_vector_type(4)));

#define GLOAD16(gp, lp) \
  __builtin_amdgcn_global_load_lds((__attribute__((address_space(1))) void*)(gp), \
                                   (__attribute__((address_space(3))) void*)(lp), 16, 0, 0)

#define WAIT_VM8() asm volatile("s_waitcnt vmcnt(8)" ::: "memory")
#define WAIT_VM0() asm volatile("s_waitcnt vmcnt(0)" ::: "memory")
#define BAR() asm volatile("s_barrier" ::: "memory")

static constexpr int T_   = 2048;
static constexpr int D_   = 2048;
static constexpr int NQ_  = 16;
static constexpr int NK_  = 4;
static constexpr int H_   = 128;
static constexpr int NQKV = 3072;   // 16*128 + 4*128 + 4*128
static constexpr int KOFF = 2048;
static constexpr int VOFF = 2560;

// ---------------- prep stage 1: X cast + all 4 weight transposes ----------------
// cast_x (blocks 0..8191) and weight transposes (8192..18431) are independent;
// one launch overlaps them and removes a launch gap.

__global__ void prep1_kernel(const float* __restrict__ X,
                             const float* __restrict__ Wq,
                             const float* __restrict__ Wk,
                             const float* __restrict__ Wv,
                             const float* __restrict__ Wo,
                             _Float16* __restrict__ Xh,
                             _Float16* __restrict__ Wqkvt,
                             _Float16* __restrict__ Wot) {
  __shared__ float tile[32][33];
  const int blk = blockIdx.x;
  const int tid = threadIdx.x;
  if (blk < 8192) {                      // cast X -> f16, float4 loads
    int i = (blk * 256 + tid) * 4;
    float4 v = *reinterpret_cast<const float4*>(X + i);
    union { _Float16 h[4]; uint2 u; } p;
    p.h[0] = (_Float16)v.x; p.h[1] = (_Float16)v.y;
    p.h[2] = (_Float16)v.z; p.h[3] = (_Float16)v.w;
    *reinterpret_cast<uint2*>(Xh + i) = p.u;
    return;
  }
  const int v = blk - 8192;              // 0..10239 -> (bx 0..159, k-block 0..63)
  const int bx = v % 160;
  const int k0 = (v / 160) * 32;
  const float* src; _Float16* dst; int ncols, n0;
  if (bx < 64)      { src = Wq; dst = Wqkvt;                       ncols = 2048; n0 = bx * 32; }
  else if (bx < 80) { src = Wk; dst = Wqkvt + (size_t)2048 * 2048; ncols = 512;  n0 = (bx - 64) * 32; }
  else if (bx < 96) { src = Wv; dst = Wqkvt + (size_t)2560 * 2048; ncols = 512;  n0 = (bx - 80) * 32; }
  else              { src = Wo; dst = Wot;                         ncols = 2048; n0 = (bx - 96) * 32; }
  const int tx = tid & 31, ty = tid >> 5;
#pragma unroll
  for (int i = 0; i < 32; i += 8)
    tile[ty + i][tx] = src[(size_t)(k0 + ty + i) * ncols + (n0 + tx)];
  __syncthreads();
#pragma unroll
  for (int i = 0; i < 32; i += 8)
    dst[(size_t)(n0 + ty + i) * 2048 + (k0 + tx)] = (_Float16)tile[tx][ty + i];
}

// ---------------- prep stage 2: RoPE(Q,K) + V transpose ----------------
// rope (blocks 0..1023) writes Q/K sections; vtrans (1024..3071) reads only
// the V section -- disjoint ranges, safe to overlap in one launch.
// rope: one thread per (m,h), sincos once for all 20 heads; Q pre-scaled by
// log2(e) so attn uses raw Q loads with exp2 softmax.
// vtrans tile padded to 34 halves: bank 17*tx mod 32, gcd(17,32)=1 -> clean.

__global__ void prep2_kernel(_Float16* __restrict__ qkv,
                             const int* __restrict__ pos,
                             _Float16* __restrict__ vt) {
  __shared__ _Float16 tile[32][34];
  const int blk = blockIdx.x;
  const int tid = threadIdx.x;
  if (blk < 1024) {                      // RoPE
    int idx = blk * 256 + tid;           // < 4096*64
    int h = idx & 63;
    int m = idx >> 6;
    float p = (float)pos[m];
    float freq = __builtin_amdgcn_exp2f(-0.2076204747f * (float)h);  // 10000^(-h/64)
    float a = p * freq;
    float s, c;
    sincosf(a, &s, &c);
    const float L = 1.4426950408889634f;
    float cq = c * L, sq = s * L;
    _Float16* base = qkv + (size_t)m * NQKV + h;
#pragma unroll
    for (int head = 0; head < 20; ++head) {
      const bool isq = head < 16;
      _Float16* ptr = isq ? (base + head * H_) : (base + KOFF + (head - 16) * H_);
      float x1 = (float)ptr[0], x2 = (float)ptr[64];
      float cc = isq ? cq : c, ss = isq ? sq : s;
      ptr[0]  = (_Float16)(x1 * cc - x2 * ss);
      ptr[64] = (_Float16)(x2 * cc + x1 * ss);
    }
    return;
  }
  const int v = blk - 1024;              // 0..2047
  const int bx = v & 63, by = (v >> 6) & 3, slab = v >> 8;   // t-tile, h-tile, b*4+kh
  const int t0 = bx * 32, h0 = by * 32;
  const int b = slab >> 2, kh = slab & 3;
  const int tx = tid & 31, ty = tid >> 5;
#pragma unroll
  for (int i = 0; i < 32; i += 8)
    tile[ty + i][tx] = qkv[(size_t)(b * T_ + t0 + ty + i) * NQKV + VOFF + kh * H_ + h0 + tx];
  __syncthreads();
#pragma unroll
  for (int i = 0; i < 32; i += 8)
    vt[(size_t)(slab * H_ + h0 + ty + i) * T_ + (t0 + tx)] = tile[tx][ty + i];
}

// ---------------- GEMM: C[M,N] = A[M,K] * Bt[N,K]^T ----------------
// 128x128 tile, BK=64, 4 waves (2x2), 4x4 16x16x32 frags/wave. Proven 875 TF
// (~96% of this structure's 912 TF ceiling); grids 768/512 fill 256 CUs.
// LDS XOR-swizzle (unit ^= row&7) via pre-swizzled global source (rule 21).

template <int OUT_F32>
__global__ __launch_bounds__(256, 2) void gemm_kernel(const _Float16* __restrict__ A,
                                                      const _Float16* __restrict__ Bt,
                                                      void* __restrict__ Cout, int N, int K) {
  __shared__ __align__(16) _Float16 As[128 * 64];
  __shared__ __align__(16) _Float16 Bs[128 * 64];
  const int tid = threadIdx.x;
  const int wave = tid >> 6, lane = tid & 63;
  const int lg = lane >> 4, lm = lane & 15;
  const int brow = blockIdx.y * 128, bcol = blockIdx.x * 128;
  const int wr = wave >> 1, wc = wave & 1;
  f32x4 acc[4][4] = {};
  for (int k0 = 0; k0 < K; k0 += 64) {
#pragma unroll
    for (int j = 0; j < 4; ++j) {
      int U = j * 256 + tid;          // 16B unit index, 8 units/row
      int row = U >> 3, u = U & 7;
      int us = u ^ (row & 7);
      GLOAD16(A + (size_t)(brow + row) * K + k0 + us * 8, (char*)As + ((j * 256 + wave * 64) << 4));
      GLOAD16(Bt + (size_t)(bcol + row) * K + k0 + us * 8, (char*)Bs + ((j * 256 + wave * 64) << 4));
    }
    __syncthreads();
#pragma unroll
    for (int kk = 0; kk < 2; ++kk) {
      half8 af[4], bf[4];
#pragma unroll
      for (int m = 0; m < 4; ++m) {
        int row = wr * 64 + m * 16 + lm;
        int u = (kk * 4 + lg) ^ (row & 7);
        af[m] = *reinterpret_cast<const half8*>(As + row * 64 + u * 8);
      }
#pragma unroll
      for (int n = 0; n < 4; ++n) {
        int row = wc * 64 + n * 16 + lm;
        int u = (kk * 4 + lg) ^ (row & 7);
        bf[n] = *reinterpret_cast<const half8*>(Bs + row * 64 + u * 8);
      }
#pragma unroll
      for (int m = 0; m < 4; ++m)
#pragma unroll
        for (int n = 0; n < 4; ++n)
          acc[m][n] = __builtin_amdgcn_mfma_f32_16x16x32_f16(af[m], bf[n], acc[m][n], 0, 0, 0);
    }
    __syncthreads();
  }
#pragma unroll
  for (int m = 0; m < 4; ++m)
#pragma unroll
    for (int n = 0; n < 4; ++n)
#pragma unroll
      for (int r = 0; r < 4; ++r) {
        size_t row = brow + wr * 64 + m * 16 + lg * 4 + r;
        size_t col = bcol + wc * 64 + n * 16 + lm;
        if constexpr (OUT_F32) ((float*)Cout)[row * N + col] = acc[m][n][r];
        else ((_Float16*)Cout)[row * N + col] = (_Float16)acc[m][n][r];
      }
}

// ---------------- flash attention (proven 72 us variant) ----------------
// Uniform-work blocks: q-tile = 64 rows (wave owns 16), tiles paired (p, 31-p)
// in-block -> every block exactly 33 KV-iterations. 512 blocks = 2/CU;
// XCD chunk = one (b,kh) K/V set. Double-buffered K/V, counted vmcnt, setprio.
// Swapped QK^T (mfma(K,Q)): lane owns one q-row -> row-reduce = 15 fmax+2 shfl.
// Q pre-scaled by log2e in rope -> raw qf loads. Defer-max THR=14 (log2).

__global__ __launch_bounds__(256, 2) void attn_kernel(const _Float16* __restrict__ qkv,
                                                      const _Float16* __restrict__ vt,
                                                      _Float16* __restrict__ attn) {
  __shared__ __align__(16) _Float16 Ks[2][64 * 128];    // [s][h], 16 units/row, u^= s&15
  __shared__ __align__(16) _Float16 Vs[2][128 * 64];    // [h][s],  8 units/row, u^= h&7
  __shared__ __align__(16) _Float16 Ps[4][16 * 64];     // per-wave [q][s], u^= q&7
  const int bid = blockIdx.x;
  const int swz = (bid & 7) * 64 + (bid >> 3);          // XCD chunk = 64 consecutive swz
  const int chunk = swz >> 6;                           // = b*4 + kh
  const int b = chunk >> 2, kh = chunk & 3;
  const int n = kh * 4 + ((swz >> 4) & 3);
  const int p = swz & 15;                               // pair index
  const int tid = threadIdx.x, wave = tid >> 6, lane = tid & 63;
  const int lg = lane >> 4, lm = lane & 15;

  auto stage = [&](int j, int buf) {
    const int s0 = j * 64;
    char* Kb = (char*)&Ks[buf][0];
    char* Vb = (char*)&Vs[buf][0];
#pragma unroll
    for (int jj = 0; jj < 4; ++jj) {   // K tile: 64 rows x 16 units
      int U = jj * 256 + tid;
      int srow = U >> 4, u = U & 15;
      int us = u ^ (srow & 15);
      GLOAD16(qkv + (size_t)(b * T_ + s0 + srow) * NQKV + KOFF + kh * H_ + us * 8,
              Kb + ((jj * 256 + wave * 64) << 4));
    }
#pragma unroll
    for (int jj = 0; jj < 4; ++jj) {   // Vt tile: 128 rows x 8 units
      int U = jj * 256 + tid;
      int hrow = U >> 3, u = U & 7;
      int us = u ^ (hrow & 7);
      GLOAD16(vt + (size_t)((b * NK_ + kh) * H_ + hrow) * T_ + s0 + us * 8,
              Vb + ((jj * 256 + wave * 64) << 4));
    }
  };

  for (int ph = 0; ph < 2; ++ph) {
    const int t = ph ? (31 - p) : p;                    // q-tile index, rows [64t, 64t+63]
    const int qbase = t * 64 + wave * 16;

    // Q fragments (already scaled by log2e in rope).
    half8 qf[4];
    const _Float16* qptr = qkv + (size_t)(b * T_ + qbase + lm) * NQKV + n * H_;
#pragma unroll
    for (int kk = 0; kk < 4; ++kk)
      qf[kk] = *reinterpret_cast<const half8*>(qptr + kk * 32 + lg * 8);

    f32x4 o[8] = {};
    float mrow_s = -1e30f, lrow_s = 0.f;

    const int nkv = t + 1;
    stage(0, 0);
    for (int it = 0; it < nkv; ++it) {
      const int cur = it & 1;
      if (it + 1 < nkv) { stage(it + 1, cur ^ 1); WAIT_VM8(); }
      else              { WAIT_VM0(); }
      BAR();
      const _Float16* Kt = &Ks[cur][0];
      const _Float16* Vt2 = &Vs[cur][0];

      // Swapped QK^T: S[ns][r] = logit(q = qbase+lm, s = it*64 + ns*16 + lg*4 + r)
      f32x4 S[4];
      __builtin_amdgcn_s_setprio(1);
#pragma unroll
      for (int ns = 0; ns < 4; ++ns) {
        half8 kf[4];
        int srow = ns * 16 + lm;
#pragma unroll
        for (int kk = 0; kk < 4; ++kk) {
          int u = (kk * 4 + lg) ^ (srow & 15);
          kf[kk] = *reinterpret_cast<const half8*>(Kt + srow * 128 + u * 8);
        }
        f32x4 a = {0.f, 0.f, 0.f, 0.f};
#pragma unroll
        for (int kk = 0; kk < 4; ++kk)
          a = __builtin_amdgcn_mfma_f32_16x16x32_f16(kf[kk], qf[kk], a, 0, 0, 0);
        S[ns] = a;
      }
      __builtin_amdgcn_s_setprio(0);

      if (it == t) {                  // diagonal tile: causal mask
        const int q = qbase + lm;
#pragma unroll
        for (int ns = 0; ns < 4; ++ns)
#pragma unroll
          for (int r = 0; r < 4; ++r) {
            int s = t * 64 + ns * 16 + lg * 4 + r;
            if (s > q) S[ns][r] = -1e30f;
          }
      }

      // Row max: 15 local fmax + 2 shfl (lanes xor16/xor32 share the q-row).
      float pm0 = fmaxf(fmaxf(S[0][0], S[0][1]), fmaxf(S[0][2], S[0][3]));
      float pm1 = fmaxf(fmaxf(S[1][0], S[1][1]), fmaxf(S[1][2], S[1][3]));
      float pm2 = fmaxf(fmaxf(S[2][0], S[2][1]), fmaxf(S[2][2], S[2][3]));
      float pm3 = fmaxf(fmaxf(S[3][0], S[3][1]), fmaxf(S[3][2], S[3][3]));
      float pm = fmaxf(fmaxf(pm0, pm1), fmaxf(pm2, pm3));
      pm = fmaxf(pm, __shfl_xor(pm, 16));
      pm = fmaxf(pm, __shfl_xor(pm, 32));

      // Defer-max: only rescale when some row's max grew past THR (log2 units).
      if (__any(pm > mrow_s + 14.f)) {
        float mn = fmaxf(mrow_s, pm);
        float sc = __builtin_amdgcn_exp2f(mrow_s - mn);
        mrow_s = mn;
        lrow_s *= sc;
        float scr[4];
#pragma unroll
        for (int r = 0; r < 4; ++r) scr[r] = __shfl(sc, lg * 4 + r);
#pragma unroll
        for (int nh = 0; nh < 8; ++nh)
#pragma unroll
          for (int r = 0; r < 4; ++r) o[nh][r] *= scr[r];
      }

      const float m = mrow_s;
      float ps = 0.f;
#pragma unroll
      for (int ns = 0; ns < 4; ++ns)
#pragma unroll
        for (int r = 0; r < 4; ++r) {
          float pv = __builtin_amdgcn_exp2f(S[ns][r] - m);
          S[ns][r] = pv;
          ps += pv;
        }
      ps += __shfl_xor(ps, 16);
      ps += __shfl_xor(ps, 32);
      lrow_s += ps;

      // P -> LDS: 4x ds_write_b64 (packed half4), same XOR swizzle as PA read.
#pragma unroll
      for (int ns = 0; ns < 4; ++ns) {
        half4 pk;
#pragma unroll
        for (int r = 0; r < 4; ++r) pk[r] = (_Float16)S[ns][r];
        int u = (2 * ns + (lg >> 1)) ^ (lm & 7);
        *reinterpret_cast<half4*>(&Ps[wave][lm * 64 + u * 8 + (lg & 1) * 4]) = pk;
      }

      __builtin_amdgcn_s_setprio(1);
#pragma unroll
      for (int kk2 = 0; kk2 < 2; ++kk2) {
        int up = (kk2 * 4 + lg) ^ (lm & 7);
        half8 pa = *reinterpret_cast<const half8*>(&Ps[wave][lm * 64 + up * 8]);
#pragma unroll
        for (int nh = 0; nh < 8; ++nh) {
          int hrow = nh * 16 + lm;
          int u = (kk2 * 4 + lg) ^ (hrow & 7);
          half8 vf = *reinterpret_cast<const half8*>(Vt2 + hrow * 64 + u * 8);
          o[nh] = __builtin_amdgcn_mfma_f32_16x16x32_f16(pa, vf, o[nh], 0, 0, 0);
        }
      }
      __builtin_amdgcn_s_setprio(0);
      BAR();
    }

    float linv[4];
#pragma unroll
    for (int r = 0; r < 4; ++r) linv[r] = 1.f / __shfl(lrow_s, lg * 4 + r);
#pragma unroll
    for (int r = 0; r < 4; ++r) {
      int q = qbase + lg * 4 + r;
      _Float16* optr = attn + ((size_t)(b * T_ + q) * NQ_ + n) * H_ + lm;
#pragma unroll
      for (int nh = 0; nh < 8; ++nh)
        optr[nh * 16] = (_Float16)(o[nh][r] * linv[r]);
    }
  }
}

// ---------------- launch ----------------

extern "C" void kernel_launch(void* const* d_in, const int* in_sizes, int n_in,
                              void* d_out, int out_size, void* d_ws, size_t ws_size,
                              hipStream_t stream) {
  const float* X  = (const float*)d_in[0];
  const int* pos  = (const int*)d_in[1];
  const float* Wq = (const float*)d_in[2];
  const float* Wk = (const float*)d_in[3];
  const float* Wv = (const float*)d_in[4];
  const float* Wo = (const float*)d_in[5];

  _Float16* Xh    = (_Float16*)d_ws;                   // 4096*2048
  _Float16* Wqkvt = Xh + (size_t)4096 * 2048;          // [3072][2048]
  _Float16* Wot   = Wqkvt + (size_t)3072 * 2048;       // [2048][2048]
  _Float16* QKV   = Wot + (size_t)2048 * 2048;         // [4096][3072]
  _Float16* Vt    = QKV + (size_t)4096 * 3072;         // [2][4][128][2048]
  _Float16* Attn  = Vt + (size_t)8 * 128 * 2048;       // [4096][2048]

  prep1_kernel<<<18432, 256, 0, stream>>>(X, Wq, Wk, Wv, Wo, Xh, Wqkvt, Wot);
  gemm_kernel<0><<<dim3(24, 32), 256, 0, stream>>>(Xh, Wqkvt, QKV, NQKV, 2048);
  prep2_kernel<<<3072, 256, 0, stream>>>(QKV, pos, Vt);
  attn_kernel<<<512, 256, 0, stream>>>(QKV, Vt, Attn);
  gemm_kernel<1><<<dim3(16, 32), 256, 0, stream>>>(Attn, Wot, d_out, 2048, 2048);
}